// Round 2
// baseline (365.034 us; speedup 1.0000x reference)
//
#include <hip/hip_runtime.h>
#include <math.h>

#define NSAMP 4096
#define DIMX  12800

// Layout of the concatenated J matrices (l=1..4) in workspace / LDS:
// l=1: [0,9)  l=2: [9,34)  l=3: [34,83)  l=4: [83,164)
#define JTOT 164

// ---------------------------------------------------------------------------
// Init kernel: recompute J_l = Re(A d^l(pi/2) A^H) in fp64, element-parallel.
// One block of 256 threads; threads 0..163 each own one (l,i,j) element.
// ---------------------------------------------------------------------------
__global__ __launch_bounds__(256) void initJ_kernel(float* __restrict__ Jout) {
    __shared__ double dm[JTOT];
    __shared__ double Ar[JTOT], Ai[JTOT];
    __shared__ double Br[JTOT], Bi[JTOT];

    const int tid = threadIdx.x;
    int l = 0, base = 0, d = 0, ii = 0, jj = 0;
    const bool act = tid < JTOT;
    if (act) {
        if (tid < 9)       { l = 1; base = 0; }
        else if (tid < 34) { l = 2; base = 9; }
        else if (tid < 83) { l = 3; base = 34; }
        else               { l = 4; base = 83; }
        d = 2 * l + 1;
        int loc = tid - base;
        ii = loc / d;           // mp row
        jj = loc - ii * d;      // m col

        // factorials 0..8
        double fact[9];
        fact[0] = 1.0;
        for (int k = 1; k < 9; k++) fact[k] = fact[k - 1] * (double)k;

        const int mp = ii - l, m = jj - l;
        const double num = sqrt(fact[l + mp] * fact[l - mp] * fact[l + m] * fact[l - m]);
        const double c2 = 0.70710678118654752440;  // cos(pi/4) == sin(pi/4)
        double tot = 0.0;
        const int s0 = (m - mp > 0) ? (m - mp) : 0;
        const int s1 = (l + m < l - mp) ? (l + m) : (l - mp);
        for (int s = s0; s <= s1; s++) {
            double den = fact[l + m - s] * fact[s] * fact[mp - m + s] * fact[l - mp - s];
            int etot = (2 * l + m - mp - 2 * s) + (mp - m + 2 * s);  // = 2l, but keep general
            double p = 1.0;
            for (int q = 0; q < etot; q++) p *= c2;
            double sgn = ((mp - m + s) & 1) ? -1.0 : 1.0;
            tot += sgn * (num / den) * p;
        }
        dm[tid] = tot;

        // Real-basis change matrix A (complex), element (ii,jj)
        double ar = 0.0, ai = 0.0;
        const double inv_s2 = 0.70710678118654752440;
        if (ii == l) {
            if (jj == l) ar = 1.0;
        } else if (ii > l) {
            int mm = ii - l;
            if (jj == l + mm)      ar = (mm & 1) ? -inv_s2 : inv_s2;  // (-1)^mm / sqrt2
            else if (jj == l - mm) ar = inv_s2;
        } else {  // ii < l
            int mm = l - ii;
            if (jj == l + mm)      ai = (mm & 1) ? inv_s2 : -inv_s2;  // -1j*(-1)^mm/sqrt2
            else if (jj == l - mm) ai = inv_s2;                        // +1j/sqrt2
        }
        Ar[tid] = ar; Ai[tid] = ai;
    }
    __syncthreads();
    if (act) {  // B = A @ dm (dm real)
        double br = 0.0, bi = 0.0;
        for (int k = 0; k < d; k++) {
            double dv = dm[base + k * d + jj];
            br += Ar[base + ii * d + k] * dv;
            bi += Ai[base + ii * d + k] * dv;
        }
        Br[tid] = br; Bi[tid] = bi;
    }
    __syncthreads();
    if (act) {  // J = Re(B @ A^H)
        double jr = 0.0;
        for (int k = 0; k < d; k++) {
            jr += Br[base + ii * d + k] * Ar[base + jj * d + k]
                + Bi[base + ii * d + k] * Ai[base + jj * d + k];
        }
        Jout[tid] = (float)jr;
    }
}

// ---------------------------------------------------------------------------
// Direct global->LDS 16B load (no VGPR round-trip). LDS dest is wave-uniform
// base + lane*16; source is per-lane. Both sides linear here (rule #21).
// ---------------------------------------------------------------------------
__device__ __forceinline__ void gload_lds16(const float4* g, float* lds) {
    __builtin_amdgcn_global_load_lds(
        (const __attribute__((address_space(1))) void*)g,
        (__attribute__((address_space(3))) void*)lds, 16, 0, 0);
}

// ---------------------------------------------------------------------------
// In-place per-group transform in LDS. Each thread owns groups {tid, tid+256}
// exclusively -> no sync needed inside. Stride-d scalar LDS access, d odd =>
// gcd(d,32)=1 => at most 2 lanes/bank (free on CDNA4). FMA order identical to
// the verified kernel.
// ---------------------------------------------------------------------------
template <int L, int SEGBASE>
__device__ __forceinline__ void xform(float* __restrict__ buf,
                                      const float* __restrict__ Dl, int tid) {
    constexpr int d = 2 * L + 1;
#pragma unroll
    for (int rep = 0; rep < 2; rep++) {
        const int g = tid + rep * 256;
        float* p = buf + SEGBASE + g * d;
        float v[d];
#pragma unroll
        for (int j = 0; j < d; j++) v[j] = p[j];
        float r[d];
#pragma unroll
        for (int i = 0; i < d; i++) {
            float acc = 0.0f;
#pragma unroll
            for (int j = 0; j < d; j++) acc = fmaf(Dl[i * d + j], v[j], acc);
            r[i] = acc;
        }
#pragma unroll
        for (int i = 0; i < d; i++) p[i] = r[i];
    }
}

// ---------------------------------------------------------------------------
// Main kernel: one block per sample. Issue the ENTIRE l>=1 row (48 KB) as
// direct global->LDS loads at kernel entry (12 x dwordx4 per thread), then
// build D while the loads stream, then one in-place transform pass and one
// uninterrupted float4 store stream. 2 phase-2 barriers instead of 12.
// ---------------------------------------------------------------------------
__global__ __launch_bounds__(256, 3) void rot_main(
    const float* __restrict__ gamma, const float* __restrict__ beta,
    const float* __restrict__ alpha, const float* __restrict__ x,
    const float* __restrict__ Jws, float* __restrict__ out) {
    __shared__ float sJ[JTOT];
    __shared__ float sD[JTOT];
    __shared__ float sT0[JTOT];
    __shared__ float sT1[JTOT];
    __shared__ float trig[3][10];  // [angle][cos0..cos4, sin0..sin4]
    __shared__ __align__(16) float xbuf[12288];  // full l>=1 row, 48 KB

    const int tid = threadIdx.x;
    const int n = blockIdx.x;

    const float* xrow = x + (size_t)n * DIMX;
    float* orow = out + (size_t)n * DIMX;

    // l=0 passthrough: issue its load first (oldest vmcnt slot -> its store
    // doesn't force draining the row loads below).
    const float2 l0 = ((const float2*)xrow)[tid];

    // Whole l>=1 row -> LDS, fire-and-forget. Segment bases inside xbuf:
    // l=1: 0, l=2: 1536, l=3: 4096, l=4: 7680 (floats).
    {
        const float4* xv4 = (const float4*)(xrow + 512);
        float* ldsw = xbuf + ((tid >> 6) << 8);  // wave-uniform base: 256*wave_id floats
#pragma unroll
        for (int q = 0; q < 12; q++)
            gload_lds16(xv4 + q * 256 + tid, ldsw + q * 1024);
    }

    ((float2*)orow)[tid] = l0;

    if (tid < JTOT) sJ[tid] = Jws[tid];
    if (tid < 30) {
        int ai = tid / 10, k = tid % 10;
        float ang = (ai == 0) ? gamma[n] : (ai == 1) ? beta[n] : alpha[n];
        trig[ai][k] = (k < 5) ? cosf((float)k * ang) : sinf((float)(k - 5) * ang);
    }
    __syncthreads();

    int l = 0, base = 0, d = 0, ii = 0, jj = 0;
    const bool act = tid < JTOT;
    if (act) {
        if (tid < 9)       { l = 1; base = 0; }
        else if (tid < 34) { l = 2; base = 9; }
        else if (tid < 83) { l = 3; base = 34; }
        else               { l = 4; base = 83; }
        d = 2 * l + 1;
        int loc = tid - base;
        ii = loc / d;
        jj = loc - ii * d;
    }
    // Stage 1: T0 = J^T @ Eg  (Eg: diag cos, antidiag -sin; sin_v[d-1-j] = -sin_v[j])
    if (act) {
        int am = jj - l, aa = (am < 0) ? -am : am;
        float cv = trig[0][aa];
        float sv = (am > 0) ? trig[0][5 + aa] : (am < 0) ? -trig[0][5 + aa] : 0.0f;
        sT0[tid] = sJ[base + jj * d + ii] * cv + sJ[base + (d - 1 - jj) * d + ii] * sv;
    }
    __syncthreads();
    // Stage 2: T1 = Eb @ T0
    if (act) {
        int am = ii - l, aa = (am < 0) ? -am : am;
        float cv = trig[1][aa];
        float sv = (am > 0) ? trig[1][5 + aa] : (am < 0) ? -trig[1][5 + aa] : 0.0f;
        sT1[tid] = cv * sT0[tid] - sv * sT0[base + (d - 1 - ii) * d + jj];
    }
    __syncthreads();
    // Stage 3: T2 = J @ T1 -> sT0 (dense, <=9 MACs)
    if (act) {
        float acc = 0.0f;
        for (int k = 0; k < d; k++)
            acc = fmaf(sJ[base + ii * d + k], sT1[base + k * d + jj], acc);
        sT0[tid] = acc;
    }
    __syncthreads();
    // Stage 4: D = Ea @ T2
    if (act) {
        int am = ii - l, aa = (am < 0) ? -am : am;
        float cv = trig[2][aa];
        float sv = (am > 0) ? trig[2][5 + aa] : (am < 0) ? -trig[2][5 + aa] : 0.0f;
        sD[tid] = cv * sT0[tid] - sv * sT0[base + (d - 1 - ii) * d + jj];
    }
    __syncthreads();  // row loads drained at the first barrier; sD now visible

    // Phase 2: one in-place transform pass (no syncs between l's), then one
    // barrier and one uninterrupted store stream.
    xform<1, 0>(xbuf, &sD[0], tid);
    xform<2, 1536>(xbuf, &sD[9], tid);
    xform<3, 4096>(xbuf, &sD[34], tid);
    xform<4, 7680>(xbuf, &sD[83], tid);
    __syncthreads();

    {
        float4* ov4 = (float4*)(orow + 512);
        const float4* bv4 = (const float4*)xbuf;
#pragma unroll
        for (int q = 0; q < 12; q++)
            ov4[q * 256 + tid] = bv4[q * 256 + tid];
    }
}

extern "C" void kernel_launch(void* const* d_in, const int* in_sizes, int n_in,
                              void* d_out, int out_size, void* d_ws, size_t ws_size,
                              hipStream_t stream) {
    const float* gamma = (const float*)d_in[0];
    const float* beta  = (const float*)d_in[1];
    const float* alpha = (const float*)d_in[2];
    const float* x     = (const float*)d_in[3];
    float* out = (float*)d_out;
    float* Jws = (float*)d_ws;  // 164 floats

    hipLaunchKernelGGL(initJ_kernel, dim3(1), dim3(256), 0, stream, Jws);
    hipLaunchKernelGGL(rot_main, dim3(NSAMP), dim3(256), 0, stream,
                       gamma, beta, alpha, x, Jws, out);
}

// Round 3
// 359.916 us; speedup vs baseline: 1.0142x; 1.0142x over previous
//
#include <hip/hip_runtime.h>
#include <math.h>

#define NSAMP 4096
#define DIMX  12800

// Layout of the concatenated J matrices (l=1..4):
// l=1: [0,9)  l=2: [9,34)  l=3: [34,83)  l=4: [83,164)
#define JTOT 164

// ---------------------------------------------------------------------------
// J passed by value as a kernel argument (656 B, kernarg segment).
// Computed ON HOST once, in fp64 with the exact op order the old initJ
// device kernel used -> bit-identical floats, no init dispatch.
// ---------------------------------------------------------------------------
struct JArg { float v[JTOT]; };

static JArg make_J_host() {
    JArg out{};
    double fact[9];
    fact[0] = 1.0;
    for (int k = 1; k < 9; k++) fact[k] = fact[k - 1] * (double)k;
    const double c2 = 0.70710678118654752440;  // cos(pi/4) == sin(pi/4) == 1/sqrt2

    int base = 0;
    for (int l = 1; l <= 4; l++) {
        const int d = 2 * l + 1;
        double dm[81], Ar[81], Ai[81], Br[81], Bi[81];

        for (int ii = 0; ii < d; ii++) {
            for (int jj = 0; jj < d; jj++) {
                const int mp = ii - l, m = jj - l;
                const double num =
                    sqrt(fact[l + mp] * fact[l - mp] * fact[l + m] * fact[l - m]);
                double tot = 0.0;
                const int s0 = (m - mp > 0) ? (m - mp) : 0;
                const int s1 = (l + m < l - mp) ? (l + m) : (l - mp);
                for (int s = s0; s <= s1; s++) {
                    double den = fact[l + m - s] * fact[s] * fact[mp - m + s] *
                                 fact[l - mp - s];
                    int etot = (2 * l + m - mp - 2 * s) + (mp - m + 2 * s);
                    double p = 1.0;
                    for (int q = 0; q < etot; q++) p *= c2;
                    double sgn = ((mp - m + s) & 1) ? -1.0 : 1.0;
                    tot += sgn * (num / den) * p;
                }
                dm[ii * d + jj] = tot;

                double ar = 0.0, ai = 0.0;
                if (ii == l) {
                    if (jj == l) ar = 1.0;
                } else if (ii > l) {
                    int mm = ii - l;
                    if (jj == l + mm)      ar = (mm & 1) ? -c2 : c2;
                    else if (jj == l - mm) ar = c2;
                } else {
                    int mm = l - ii;
                    if (jj == l + mm)      ai = (mm & 1) ? c2 : -c2;
                    else if (jj == l - mm) ai = c2;
                }
                Ar[ii * d + jj] = ar; Ai[ii * d + jj] = ai;
            }
        }
        // B = A @ dm (dm real)
        for (int ii = 0; ii < d; ii++)
            for (int jj = 0; jj < d; jj++) {
                double br = 0.0, bi = 0.0;
                for (int k = 0; k < d; k++) {
                    double dv = dm[k * d + jj];
                    br += Ar[ii * d + k] * dv;
                    bi += Ai[ii * d + k] * dv;
                }
                Br[ii * d + jj] = br; Bi[ii * d + jj] = bi;
            }
        // J = Re(B @ A^H)
        for (int ii = 0; ii < d; ii++)
            for (int jj = 0; jj < d; jj++) {
                double jr = 0.0;
                for (int k = 0; k < d; k++)
                    jr += Br[ii * d + k] * Ar[jj * d + k] +
                          Bi[ii * d + k] * Ai[jj * d + k];
                out.v[base + ii * d + jj] = (float)jr;
            }
        base += d * d;
    }
    return out;
}

// ---------------------------------------------------------------------------
// Direct global->LDS 16B load (no VGPR round-trip). LDS dest is wave-uniform
// base + lane*16; source is per-lane. Both sides linear here (rule #21).
// ---------------------------------------------------------------------------
__device__ __forceinline__ void gload_lds16(const float4* g, float* lds) {
    __builtin_amdgcn_global_load_lds(
        (const __attribute__((address_space(1))) void*)g,
        (__attribute__((address_space(3))) void*)lds, 16, 0, 0);
}

// ---------------------------------------------------------------------------
// In-place per-group transform in LDS. Each thread owns groups {tid, tid+256}
// exclusively -> no sync needed inside. Stride-d scalar LDS access, d odd =>
// gcd(d,32)=1 => at most 2 lanes/bank (free on CDNA4). FMA order identical to
// the verified kernel.
// ---------------------------------------------------------------------------
template <int L, int SEGBASE>
__device__ __forceinline__ void xform(float* __restrict__ buf,
                                      const float* __restrict__ Dl, int tid) {
    constexpr int d = 2 * L + 1;
#pragma unroll
    for (int rep = 0; rep < 2; rep++) {
        const int g = tid + rep * 256;
        float* p = buf + SEGBASE + g * d;
        float v[d];
#pragma unroll
        for (int j = 0; j < d; j++) v[j] = p[j];
        float r[d];
#pragma unroll
        for (int i = 0; i < d; i++) {
            float acc = 0.0f;
#pragma unroll
            for (int j = 0; j < d; j++) acc = fmaf(Dl[i * d + j], v[j], acc);
            r[i] = acc;
        }
#pragma unroll
        for (int i = 0; i < d; i++) p[i] = r[i];
    }
}

// ---------------------------------------------------------------------------
// Main kernel: one block per sample. Issue the ENTIRE l>=1 row (48 KB) as
// direct global->LDS loads at kernel entry (12 x dwordx4 per thread), then
// build D while the loads stream, then one in-place transform pass and one
// uninterrupted float4 store stream. Single dispatch per iteration.
// ---------------------------------------------------------------------------
__global__ __launch_bounds__(256, 3) void rot_main(
    const float* __restrict__ gamma, const float* __restrict__ beta,
    const float* __restrict__ alpha, const float* __restrict__ x,
    const JArg Jarg, float* __restrict__ out) {
    __shared__ float sJ[JTOT];
    __shared__ float sD[JTOT];
    __shared__ float sT0[JTOT];
    __shared__ float sT1[JTOT];
    __shared__ float trig[3][10];  // [angle][cos0..cos4, sin0..sin4]
    __shared__ __align__(16) float xbuf[12288];  // full l>=1 row, 48 KB

    const int tid = threadIdx.x;
    const int n = blockIdx.x;

    const float* xrow = x + (size_t)n * DIMX;
    float* orow = out + (size_t)n * DIMX;

    // l=0 passthrough: issue its load first (oldest vmcnt slot -> its store
    // doesn't force draining the row loads below).
    const float2 l0 = ((const float2*)xrow)[tid];

    // Whole l>=1 row -> LDS, fire-and-forget. Segment bases inside xbuf:
    // l=1: 0, l=2: 1536, l=3: 4096, l=4: 7680 (floats).
    {
        const float4* xv4 = (const float4*)(xrow + 512);
        float* ldsw = xbuf + ((tid >> 6) << 8);  // wave-uniform base: 256*wave_id floats
#pragma unroll
        for (int q = 0; q < 12; q++)
            gload_lds16(xv4 + q * 256 + tid, ldsw + q * 1024);
    }

    ((float2*)orow)[tid] = l0;

    if (tid < JTOT) sJ[tid] = Jarg.v[tid];  // kernarg segment, cached
    if (tid < 30) {
        int ai = tid / 10, k = tid % 10;
        float ang = (ai == 0) ? gamma[n] : (ai == 1) ? beta[n] : alpha[n];
        trig[ai][k] = (k < 5) ? cosf((float)k * ang) : sinf((float)(k - 5) * ang);
    }
    __syncthreads();

    int l = 0, base = 0, d = 0, ii = 0, jj = 0;
    const bool act = tid < JTOT;
    if (act) {
        if (tid < 9)       { l = 1; base = 0; }
        else if (tid < 34) { l = 2; base = 9; }
        else if (tid < 83) { l = 3; base = 34; }
        else               { l = 4; base = 83; }
        d = 2 * l + 1;
        int loc = tid - base;
        ii = loc / d;
        jj = loc - ii * d;
    }
    // Stage 1: T0 = J^T @ Eg  (Eg: diag cos, antidiag -sin; sin_v[d-1-j] = -sin_v[j])
    if (act) {
        int am = jj - l, aa = (am < 0) ? -am : am;
        float cv = trig[0][aa];
        float sv = (am > 0) ? trig[0][5 + aa] : (am < 0) ? -trig[0][5 + aa] : 0.0f;
        sT0[tid] = sJ[base + jj * d + ii] * cv + sJ[base + (d - 1 - jj) * d + ii] * sv;
    }
    __syncthreads();
    // Stage 2: T1 = Eb @ T0
    if (act) {
        int am = ii - l, aa = (am < 0) ? -am : am;
        float cv = trig[1][aa];
        float sv = (am > 0) ? trig[1][5 + aa] : (am < 0) ? -trig[1][5 + aa] : 0.0f;
        sT1[tid] = cv * sT0[tid] - sv * sT0[base + (d - 1 - ii) * d + jj];
    }
    __syncthreads();
    // Stage 3: T2 = J @ T1 -> sT0 (dense, <=9 MACs)
    if (act) {
        float acc = 0.0f;
        for (int k = 0; k < d; k++)
            acc = fmaf(sJ[base + ii * d + k], sT1[base + k * d + jj], acc);
        sT0[tid] = acc;
    }
    __syncthreads();
    // Stage 4: D = Ea @ T2
    if (act) {
        int am = ii - l, aa = (am < 0) ? -am : am;
        float cv = trig[2][aa];
        float sv = (am > 0) ? trig[2][5 + aa] : (am < 0) ? -trig[2][5 + aa] : 0.0f;
        sD[tid] = cv * sT0[tid] - sv * sT0[base + (d - 1 - ii) * d + jj];
    }
    __syncthreads();  // row loads drained at the first barrier; sD now visible

    // Phase 2: one in-place transform pass (no syncs between l's), then one
    // barrier and one uninterrupted store stream.
    xform<1, 0>(xbuf, &sD[0], tid);
    xform<2, 1536>(xbuf, &sD[9], tid);
    xform<3, 4096>(xbuf, &sD[34], tid);
    xform<4, 7680>(xbuf, &sD[83], tid);
    __syncthreads();

    {
        float4* ov4 = (float4*)(orow + 512);
        const float4* bv4 = (const float4*)xbuf;
#pragma unroll
        for (int q = 0; q < 12; q++)
            ov4[q * 256 + tid] = bv4[q * 256 + tid];
    }
}

extern "C" void kernel_launch(void* const* d_in, const int* in_sizes, int n_in,
                              void* d_out, int out_size, void* d_ws, size_t ws_size,
                              hipStream_t stream) {
    const float* gamma = (const float*)d_in[0];
    const float* beta  = (const float*)d_in[1];
    const float* alpha = (const float*)d_in[2];
    const float* x     = (const float*)d_in[3];
    float* out = (float*)d_out;
    (void)d_ws; (void)ws_size;

    static const JArg jarg = make_J_host();  // host-side, computed once

    hipLaunchKernelGGL(rot_main, dim3(NSAMP), dim3(256), 0, stream,
                       gamma, beta, alpha, x, jarg, out);
}

// Round 4
// 354.815 us; speedup vs baseline: 1.0288x; 1.0144x over previous
//
#include <hip/hip_runtime.h>
#include <math.h>

#define NSAMP 4096
#define DIMX  12800

// Layout of the concatenated J matrices (l=1..4):
// l=1: [0,9)  l=2: [9,34)  l=3: [34,83)  l=4: [83,164)
#define JTOT 164

// ---------------------------------------------------------------------------
// J passed by value as a kernel argument (656 B, kernarg segment).
// Computed ON HOST once, in fp64 with the exact op order the original initJ
// device kernel used -> bit-identical floats, no init dispatch.
// ---------------------------------------------------------------------------
struct JArg { float v[JTOT]; };

static JArg make_J_host() {
    JArg out{};
    double fact[9];
    fact[0] = 1.0;
    for (int k = 1; k < 9; k++) fact[k] = fact[k - 1] * (double)k;
    const double c2 = 0.70710678118654752440;  // cos(pi/4) == sin(pi/4) == 1/sqrt2

    int base = 0;
    for (int l = 1; l <= 4; l++) {
        const int d = 2 * l + 1;
        double dm[81], Ar[81], Ai[81], Br[81], Bi[81];

        for (int ii = 0; ii < d; ii++) {
            for (int jj = 0; jj < d; jj++) {
                const int mp = ii - l, m = jj - l;
                const double num =
                    sqrt(fact[l + mp] * fact[l - mp] * fact[l + m] * fact[l - m]);
                double tot = 0.0;
                const int s0 = (m - mp > 0) ? (m - mp) : 0;
                const int s1 = (l + m < l - mp) ? (l + m) : (l - mp);
                for (int s = s0; s <= s1; s++) {
                    double den = fact[l + m - s] * fact[s] * fact[mp - m + s] *
                                 fact[l - mp - s];
                    int etot = (2 * l + m - mp - 2 * s) + (mp - m + 2 * s);
                    double p = 1.0;
                    for (int q = 0; q < etot; q++) p *= c2;
                    double sgn = ((mp - m + s) & 1) ? -1.0 : 1.0;
                    tot += sgn * (num / den) * p;
                }
                dm[ii * d + jj] = tot;

                double ar = 0.0, ai = 0.0;
                if (ii == l) {
                    if (jj == l) ar = 1.0;
                } else if (ii > l) {
                    int mm = ii - l;
                    if (jj == l + mm)      ar = (mm & 1) ? -c2 : c2;
                    else if (jj == l - mm) ar = c2;
                } else {
                    int mm = l - ii;
                    if (jj == l + mm)      ai = (mm & 1) ? c2 : -c2;
                    else if (jj == l - mm) ai = c2;
                }
                Ar[ii * d + jj] = ar; Ai[ii * d + jj] = ai;
            }
        }
        // B = A @ dm (dm real)
        for (int ii = 0; ii < d; ii++)
            for (int jj = 0; jj < d; jj++) {
                double br = 0.0, bi = 0.0;
                for (int k = 0; k < d; k++) {
                    double dv = dm[k * d + jj];
                    br += Ar[ii * d + k] * dv;
                    bi += Ai[ii * d + k] * dv;
                }
                Br[ii * d + jj] = br; Bi[ii * d + jj] = bi;
            }
        // J = Re(B @ A^H)
        for (int ii = 0; ii < d; ii++)
            for (int jj = 0; jj < d; jj++) {
                double jr = 0.0;
                for (int k = 0; k < d; k++)
                    jr += Br[ii * d + k] * Ar[jj * d + k] +
                          Bi[ii * d + k] * Ai[jj * d + k];
                out.v[base + ii * d + jj] = (float)jr;
            }
        base += d * d;
    }
    return out;
}

// ---------------------------------------------------------------------------
// Direct global->LDS 16B load (no VGPR round-trip). LDS dest is wave-uniform
// base + lane*16; source is per-lane. Both sides linear here (rule #21).
// ---------------------------------------------------------------------------
__device__ __forceinline__ void gload_lds16(const float4* g, float* lds) {
    __builtin_amdgcn_global_load_lds(
        (const __attribute__((address_space(1))) void*)g,
        (__attribute__((address_space(3))) void*)lds, 16, 0, 0);
}

// ---------------------------------------------------------------------------
// In-place per-group transform in LDS. Each thread owns groups {tid, tid+256}
// exclusively -> no sync needed inside. Stride-d scalar LDS access, d odd =>
// gcd(d,32)=1 => at most 2 lanes/bank (free on CDNA4). FMA order identical to
// the verified kernel.
// ---------------------------------------------------------------------------
template <int L, int SEGBASE>
__device__ __forceinline__ void xform(float* __restrict__ buf,
                                      const float* __restrict__ Dl, int tid) {
    constexpr int d = 2 * L + 1;
#pragma unroll
    for (int rep = 0; rep < 2; rep++) {
        const int g = tid + rep * 256;
        float* p = buf + SEGBASE + g * d;
        float v[d];
#pragma unroll
        for (int j = 0; j < d; j++) v[j] = p[j];
        float r[d];
#pragma unroll
        for (int i = 0; i < d; i++) {
            float acc = 0.0f;
#pragma unroll
            for (int j = 0; j < d; j++) acc = fmaf(Dl[i * d + j], v[j], acc);
            r[i] = acc;
        }
#pragma unroll
        for (int i = 0; i < d; i++) p[i] = r[i];
    }
}

// ---------------------------------------------------------------------------
// Main kernel, pipelined (T3/T4): all small VMEM + D-build first (normal
// barriers drain everything -> vmcnt FIFO empty), THEN issue the 12 row
// loads so the FIFO is exactly [L0..L11] in every wave, then counted-vmcnt
// chunk pipeline: compute chunk c while chunks c+1.. still stream. Raw
// s_barrier (no vmcnt(0) drain) between phases.
//   chunk0 = loads 0-3  -> floats [0,4096)    = l1 [0,1536) + l2 [1536,4096)
//   chunk1 = loads 4-7  -> floats [4096,8192) ⊇ l3 [4096,7680)
//   chunk2 = loads 8-11 -> floats [8192,12288); l4 = [7680,12288)
// ---------------------------------------------------------------------------
__global__ __launch_bounds__(256, 3) void rot_main(
    const float* __restrict__ gamma, const float* __restrict__ beta,
    const float* __restrict__ alpha, const float* __restrict__ x,
    const JArg Jarg, float* __restrict__ out) {
    __shared__ float sJ[JTOT];
    __shared__ float sD[JTOT];
    __shared__ float sT0[JTOT];
    __shared__ float sT1[JTOT];
    __shared__ float trig[3][10];  // [angle][cos0..cos4, sin0..sin4]
    __shared__ __align__(16) float xbuf[12288];  // full l>=1 row, 48 KB

    const int tid = threadIdx.x;
    const int n = blockIdx.x;

    const float* xrow = x + (size_t)n * DIMX;
    float* orow = out + (size_t)n * DIMX;

    // ---- Phase A: small VMEM + l0 passthrough + D-build (normal barriers) ----
    const float2 l0 = ((const float2*)xrow)[tid];
    if (tid < JTOT) sJ[tid] = Jarg.v[tid];
    if (tid < 30) {
        int ai = tid / 10, k = tid % 10;
        float ang = (ai == 0) ? gamma[n] : (ai == 1) ? beta[n] : alpha[n];
        trig[ai][k] = (k < 5) ? cosf((float)k * ang) : sinf((float)(k - 5) * ang);
    }
    ((float2*)orow)[tid] = l0;
    __syncthreads();  // drains ALL small vmem -> vmcnt FIFO empty after here

    int l = 0, base = 0, d = 0, ii = 0, jj = 0;
    const bool act = tid < JTOT;
    if (act) {
        if (tid < 9)       { l = 1; base = 0; }
        else if (tid < 34) { l = 2; base = 9; }
        else if (tid < 83) { l = 3; base = 34; }
        else               { l = 4; base = 83; }
        d = 2 * l + 1;
        int loc = tid - base;
        ii = loc / d;
        jj = loc - ii * d;
    }
    // Stage 1: T0 = J^T @ Eg
    if (act) {
        int am = jj - l, aa = (am < 0) ? -am : am;
        float cv = trig[0][aa];
        float sv = (am > 0) ? trig[0][5 + aa] : (am < 0) ? -trig[0][5 + aa] : 0.0f;
        sT0[tid] = sJ[base + jj * d + ii] * cv + sJ[base + (d - 1 - jj) * d + ii] * sv;
    }
    __syncthreads();
    // Stage 2: T1 = Eb @ T0
    if (act) {
        int am = ii - l, aa = (am < 0) ? -am : am;
        float cv = trig[1][aa];
        float sv = (am > 0) ? trig[1][5 + aa] : (am < 0) ? -trig[1][5 + aa] : 0.0f;
        sT1[tid] = cv * sT0[tid] - sv * sT0[base + (d - 1 - ii) * d + jj];
    }
    __syncthreads();
    // Stage 3: T2 = J @ T1 -> sT0
    if (act) {
        float acc = 0.0f;
        for (int k = 0; k < d; k++)
            acc = fmaf(sJ[base + ii * d + k], sT1[base + k * d + jj], acc);
        sT0[tid] = acc;
    }
    __syncthreads();
    // Stage 4: D = Ea @ T2
    if (act) {
        int am = ii - l, aa = (am < 0) ? -am : am;
        float cv = trig[2][aa];
        float sv = (am > 0) ? trig[2][5 + aa] : (am < 0) ? -trig[2][5 + aa] : 0.0f;
        sD[tid] = cv * sT0[tid] - sv * sT0[base + (d - 1 - ii) * d + jj];
    }
    __syncthreads();  // sD visible everywhere; vmcnt FIFO still empty

    // ---- Phase B: issue row loads with a clean vmcnt FIFO ----
    {
        const float4* xv4 = (const float4*)(xrow + 512);
        float* ldsw = xbuf + ((tid >> 6) << 8);  // wave-uniform base
#pragma unroll
        for (int q = 0; q < 12; q++)
            gload_lds16(xv4 + q * 256 + tid, ldsw + q * 1024);
    }

    // ---- Phase C: counted-vmcnt chunk pipeline (raw barriers, no drain) ----
    // chunk0 arrived (loads 0-3 retired):
    asm volatile("s_waitcnt vmcnt(8)" ::: "memory");
    __builtin_amdgcn_s_barrier();
    xform<1, 0>(xbuf, &sD[0], tid);
    xform<2, 1536>(xbuf, &sD[9], tid);
    // chunk1 arrived (loads 4-7 retired):
    asm volatile("s_waitcnt vmcnt(4)" ::: "memory");
    __builtin_amdgcn_s_barrier();
    xform<3, 4096>(xbuf, &sD[34], tid);
    // chunk2 arrived (all loads retired):
    asm volatile("s_waitcnt vmcnt(0)" ::: "memory");
    __builtin_amdgcn_s_barrier();
    xform<4, 7680>(xbuf, &sD[83], tid);

    // all in-place writes visible, then one uninterrupted store stream
    asm volatile("s_waitcnt lgkmcnt(0)" ::: "memory");
    __builtin_amdgcn_s_barrier();
    {
        float4* ov4 = (float4*)(orow + 512);
        const float4* bv4 = (const float4*)xbuf;
#pragma unroll
        for (int q = 0; q < 12; q++)
            ov4[q * 256 + tid] = bv4[q * 256 + tid];
    }
}

extern "C" void kernel_launch(void* const* d_in, const int* in_sizes, int n_in,
                              void* d_out, int out_size, void* d_ws, size_t ws_size,
                              hipStream_t stream) {
    const float* gamma = (const float*)d_in[0];
    const float* beta  = (const float*)d_in[1];
    const float* alpha = (const float*)d_in[2];
    const float* x     = (const float*)d_in[3];
    float* out = (float*)d_out;
    (void)d_ws; (void)ws_size;

    static const JArg jarg = make_J_host();  // host-side, computed once

    hipLaunchKernelGGL(rot_main, dim3(NSAMP), dim3(256), 0, stream,
                       gamma, beta, alpha, x, jarg, out);
}